// Round 15
// baseline (528.320 us; speedup 1.0000x reference)
//
#include <hip/hip_runtime.h>
#include <hip/hip_bf16.h>

#define HH 56
#define WWD 56
#define CC 384
#define HWW (HH*WWD)         // 3136
#define MM (16*HWW)          // 50176
#define MBPB 49              // M-blocks (of 64) per batch: 49*64 = 3136 exactly
#define NBLK3 (16*MBPB)      // 784 = 8*98
#define WB_BSTRIDE (24*24576) // 589824 bytes per batch in wB3
#define BSTR 396             // wfold bounce row stride (bytes)

typedef __attribute__((ext_vector_type(8))) short bf16x8;
typedef __attribute__((ext_vector_type(4))) int   int4v;
typedef __attribute__((ext_vector_type(4))) float f32x4;

__device__ __forceinline__ unsigned short f2bf(float f) {
    union { float f; unsigned u; } v; v.f = f;
    unsigned r = v.u + 0x7fffu + ((v.u >> 16) & 1u);
    return (unsigned short)(r >> 16);
}
__device__ __forceinline__ float bf2f(unsigned short h) {
    union { unsigned u; float f; } v; v.u = ((unsigned)h) << 16;
    return v.f;
}
__device__ __forceinline__ bf16x8 asbf(int4v v) {
    union { int4v i; bf16x8 b; } u; u.i = v; return u.b;
}

// K-permutation: [d=+2 (48) | +1 (96) | 0 (96) | -1 (96) | -2 (48)], d[c%8]={2,1,0,-1,-2,-1,0,1}
__device__ __forceinline__ int invp(int k) {
    if (k < 48)  return 8*k;
    if (k < 144) { int j = k-48;  return 8*(j>>1) + ((j&1) ? 7 : 1); }
    if (k < 240) { int j = k-144; return 8*(j>>1) + ((j&1) ? 6 : 2); }
    if (k < 336) { int j = k-240; return 8*(j>>1) + ((j&1) ? 5 : 3); }
    return 8*(k-336) + 4;
}
__device__ __forceinline__ int fwdp(int c) {
    int q = c >> 3, s = c & 7;
    switch (s) {
        case 0: return q;
        case 1: return 48 + 2*q;
        case 7: return 49 + 2*q;
        case 2: return 144 + 2*q;
        case 6: return 145 + 2*q;
        case 3: return 240 + 2*q;
        case 5: return 241 + 2*q;
        default: return 336 + q;
    }
}
__device__ __forceinline__ int dcls(int k) {
    return k < 48 ? 2 : k < 144 ? 1 : k < 240 ? 0 : k < 336 ? -1 : -2;
}

// x (B,H,W,C) fp32 -> xt (B,W,H,Cperm) bf16 + row sums R[b*56+h][k']
// 8-row LDS chunks (14 barriers vs 112), paired u32 stores, register R accum.
__global__ __launch_bounds__(384)
void prep_x(const float* __restrict__ x, unsigned short* __restrict__ xt,
            float* __restrict__ R)
{
    __shared__ float buf[8][CC];
    __shared__ float rsum[2][CC];
    int bid = blockIdx.x;            // b*56 + h
    int b = bid / HH, h = bid - b*HH;
    int t = threadIdx.x;
    int ws0 = t / 96, q0 = t - ws0*96;        // load role: rows ws0, ws0+4; quad q0
    int kd0 = fwdp(4*q0), kd1 = fwdp(4*q0+1), kd2 = fwdp(4*q0+2), kd3 = fwdp(4*q0+3);
    int p  = t % 192, rg = t / 192;           // store role: pair p, row-group rg
    const float* xp = x + ((size_t)bid*WWD)*CC;
    unsigned* xo = (unsigned*)(xt + ((size_t)b*HWW + h)*CC);
    float rs0 = 0.f, rs1 = 0.f;
    for (int w0 = 0; w0 < WWD; w0 += 8) {
        float4 v0 = *(const float4*)(xp + (size_t)(w0 + ws0)*CC + 4*q0);
        float4 v1 = *(const float4*)(xp + (size_t)(w0 + ws0 + 4)*CC + 4*q0);
        buf[ws0][kd0] = v0.x; buf[ws0][kd1] = v0.y;
        buf[ws0][kd2] = v0.z; buf[ws0][kd3] = v0.w;
        buf[ws0+4][kd0] = v1.x; buf[ws0+4][kd1] = v1.y;
        buf[ws0+4][kd2] = v1.z; buf[ws0+4][kd3] = v1.w;
        __syncthreads();
        #pragma unroll
        for (int it = 0; it < 4; ++it) {
            int row = it*2 + rg;
            float a0 = buf[row][2*p], a1 = buf[row][2*p+1];
            rs0 += a0; rs1 += a1;
            xo[(((size_t)(w0 + row)*HH*CC) >> 1) + p] =
                (unsigned)f2bf(a0) | ((unsigned)f2bf(a1) << 16);
        }
        __syncthreads();
    }
    rsum[rg][2*p] = rs0; rsum[rg][2*p+1] = rs1;
    __syncthreads();
    R[(size_t)bid*CC + t] = rsum[0][t] + rsum[1][t];
}

// fused mean (border-corrected, 4x redundant) + partial dual matvec quarter
__global__ __launch_bounds__(384)
void mavec_k(const float* __restrict__ R,
             const float* __restrict__ w_h, const float* __restrict__ w_c,
             float2* __restrict__ part)
{
    __shared__ float mh[CC], mc[CC];
    int p = blockIdx.x, b = blockIdx.y, t = threadIdx.x;
    const float* Rb = R + (size_t)b*HH*CC;
    float S = 0.f;
    #pragma unroll 8
    for (int hh = 0; hh < HH; ++hh) S += Rb[(size_t)hh*CC + t];
    int d = dcls(t);
    float adj = 0.f;
    if (d == 2)       adj = Rb[0*CC + t] + Rb[1*CC + t];
    else if (d == 1)  adj = Rb[0*CC + t];
    else if (d == -1) adj = Rb[55*CC + t];
    else if (d == -2) adj = Rb[54*CC + t] + Rb[55*CC + t];
    const float inv = 1.f / (float)HWW;
    int c = invp(t);
    mh[c] = (S - adj) * inv;
    mc[c] = S * inv;
    __syncthreads();
    const float* ph = w_h + (size_t)(96*p)*CC + t;
    const float* pc = w_c + (size_t)(96*p)*CC + t;
    float sh = 0.f, sc = 0.f;
    #pragma unroll 8
    for (int e = 0; e < 96; ++e) {
        sh += mh[96*p + e] * ph[(size_t)e*CC];
        sc += mc[96*p + e] * pc[(size_t)e*CC];
    }
    part[((size_t)b*4 + p)*CC + t] = make_float2(sh, sc);
}

// combine partials -> a -> GELU MLP -> softmax -> lam + biasc = lh*b_h + lc*b_c
__global__ __launch_bounds__(384)
void lam_fin(const float2* __restrict__ part,
             const float* __restrict__ b_h, const float* __restrict__ b_c,
             const float* __restrict__ w_r1, const float* __restrict__ b_r1,
             const float* __restrict__ w_r2, const float* __restrict__ b_r2,
             float2* __restrict__ lam, float* __restrict__ biasc)
{
    __shared__ float aa[CC], r1p[4][96];
    int b = blockIdx.x, t = threadIdx.x;
    float2 p0 = part[((size_t)b*4 + 0)*CC + t];
    float2 p1 = part[((size_t)b*4 + 1)*CC + t];
    float2 p2 = part[((size_t)b*4 + 2)*CC + t];
    float2 p3 = part[((size_t)b*4 + 3)*CC + t];
    float sh = p0.x + p1.x + p2.x + p3.x;
    float sc = p0.y + p1.y + p2.y + p3.y;
    aa[t] = 2.f*(sh + b_h[t]) + (sc + b_c[t]);
    __syncthreads();
    {
        int j = t % 96, p = t / 96;
        float s = 0.f;
        #pragma unroll 8
        for (int k = p*96; k < p*96 + 96; ++k) s += aa[k] * w_r1[(size_t)k*96 + j];
        r1p[p][j] = s;
    }
    __syncthreads();
    if (t < 96) {
        float s = r1p[0][t] + r1p[1][t] + r1p[2][t] + r1p[3][t] + b_r1[t];
        r1p[0][t] = 0.5f*s*(1.f + erff(s*0.70710678118654752f));
    }
    __syncthreads();
    float s0 = b_r2[3*t], s1 = b_r2[3*t+1], s2 = b_r2[3*t+2];
    #pragma unroll 8
    for (int q = 0; q < 96; ++q) {
        float rv = r1p[0][q];
        const float* wp = w_r2 + (size_t)q*(3*CC) + 3*t;
        s0 += rv*wp[0]; s1 += rv*wp[1]; s2 += rv*wp[2];
    }
    float mx = fmaxf(s0, fmaxf(s1, s2));
    float e0 = expf(s0-mx), e1 = expf(s1-mx), e2 = expf(s2-mx);
    float dn = 1.f/(e0+e1+e2);
    float lh = (e0+e1)*dn, lc = e2*dn;
    lam[(size_t)b*CC + t] = make_float2(lh, lc);
    biasc[(size_t)b*CC + t] = lh*b_h[t] + lc*b_c[t];
}

// wP3: w_p in register-fragment order (12 tiles, K=384)
__global__ __launch_bounds__(256)
void prepP_k(const float* __restrict__ w_p, char* __restrict__ wP3)
{
    int j = blockIdx.x*256 + threadIdx.x;     // 12*1536
    int kt = j / 1536, f = j - kt*1536;
    int wnx = f / 384, r = f - wnx*384;
    int ni = r / 64, lane = r - ni*64;
    int n = wnx*96 + ni*16 + (lane & 15);
    int k0 = kt*32 + ((lane >> 4) << 3);
    bf16x8 o;
    #pragma unroll
    for (int e = 0; e < 8; ++e) o[e] = (short)f2bf(w_p[(size_t)(k0 + e)*CC + n]);
    *(bf16x8*)(wP3 + (size_t)kt*24576 + wnx*6144 + ni*1024 + lane*16) = o;
}

// Weight fold, N-split (256 blocks): block (kq, which, b, np) computes
// Wcomb[which*384 + kq*96 + row][np*192 + pl] and writes wB3 fragments directly.
__global__ __launch_bounds__(512, 2)
void wfold_k(const float* __restrict__ w_h, const float* __restrict__ w_c,
             const float2* __restrict__ lam, const char* __restrict__ wP3,
             char* __restrict__ wB3)
{
    __shared__ char Asm[96*768];   // 73,728 B; bounce region aliases (96 x BSTR)
    const int tid = threadIdx.x;
    const int kq = blockIdx.x, which = blockIdx.y;
    const int b = blockIdx.z >> 1, np = blockIdx.z & 1;

    const int lane = tid & 63;
    const int wid  = tid >> 6;
    const int l16  = lane & 15;
    const int lhi  = lane >> 4;
    const int mg  = wid >> 2;                     // 2 M-groups, 48 rows each
    const int nw  = wid & 3;
    const int panel = np*2 + (nw >> 1);           // wnx panel (96 cols)
    const int sub   = nw & 1;                     // ni-half within panel

    const char* bptr = wP3 + panel*6144 + sub*3072 + lane*16;
    const float* wsrc = which ? w_c : w_h;

    int4v bb[3][3];
    #pragma unroll
    for (int e = 0; e < 3; ++e) bb[0][e] = *(const int4v*)(bptr + e*1024);
    #pragma unroll
    for (int e = 0; e < 3; ++e) bb[1][e] = *(const int4v*)(bptr + 24576 + e*1024);

    // stage A: 96 rows x 48 octs (lam-scaled bf16, oct-XOR swizzle, stride 768)
    #pragma unroll
    for (int it = 0; it < 9; ++it) {
        int s = it*512 + tid;
        if (s < 96*48) {
            int rr = s / 48, oct = s - rr*48;
            int c = invp(kq*96 + rr);
            const float* src = wsrc + (size_t)c*CC + oct*8;
            const float2* lp = lam + (size_t)b*CC + oct*8;
            bf16x8 o;
            #pragma unroll
            for (int e = 0; e < 8; ++e) {
                float2 L = lp[e];
                float s_ = which ? L.y : L.x;
                o[e] = (short)f2bf(src[e] * s_);
            }
            *(bf16x8*)(Asm + rr*768 + ((oct ^ (rr & 7)) << 4)) = o;
        }
    }

    f32x4 acc[3][3];
    #pragma unroll
    for (int mi = 0; mi < 3; ++mi)
        #pragma unroll
        for (int e = 0; e < 3; ++e) acc[mi][e] = (f32x4)0.f;

    int4v a[3];
    __syncthreads();

    #pragma unroll
    for (int kt = 0; kt < 12; ++kt) {
        if (kt + 2 < 12) {
            const char* nb = bptr + (size_t)(kt+2)*24576;
            #pragma unroll
            for (int e = 0; e < 3; ++e)
                bb[(kt+2) % 3][e] = *(const int4v*)(nb + e*1024);
        }
        const int octg = kt*4 + lhi;
        #pragma unroll
        for (int mi = 0; mi < 3; ++mi) {
            int r = mg*48 + mi*16 + l16;
            a[mi] = *(const int4v*)(Asm + r*768 + ((octg ^ (r & 7)) << 4));
        }
        #pragma unroll
        for (int mi = 0; mi < 3; ++mi)
            #pragma unroll
            for (int e = 0; e < 3; ++e)
                acc[mi][e] = __builtin_amdgcn_mfma_f32_16x16x32_bf16(
                    asbf(a[mi]), asbf(bb[kt % 3][e]), acc[mi][e], 0, 0, 0);
    }

    __syncthreads();   // done reading A region

    // bounce: acc -> LDS[row][pl] bf16, stride BSTR (pl local col 0..191)
    #pragma unroll
    for (int e = 0; e < 3; ++e) {
        int pl = (nw >> 1)*96 + sub*48 + e*16 + l16;
        #pragma unroll
        for (int mi = 0; mi < 3; ++mi) {
            int row0 = mg*48 + mi*16 + lhi*4;
            #pragma unroll
            for (int j = 0; j < 4; ++j)
                *(unsigned short*)(Asm + (row0 + j)*BSTR + pl*2) = f2bf(acc[mi][e][j]);
        }
    }
    __syncthreads();

    // gather fragments: 3 skt x 2 ph x 6 ni2 x 64 lanes = 2304 frags (5 iters)
    #pragma unroll
    for (int fi = 0; fi < 5; ++fi) {
        int flat = fi*512 + tid;
        if (flat < 2304) {
            int lane2 = flat & 63;
            int t2 = flat >> 6;
            int ni2 = t2 % 6;
            int t3 = t2 / 6;
            int ph = t3 & 1;
            int skt = t3 >> 1;
            int pl = ph*96 + ni2*16 + (lane2 & 15);
            int rl0 = skt*32 + ((lane2 >> 4) << 3);
            bf16x8 o;
            #pragma unroll
            for (int e = 0; e < 8; ++e)
                o[e] = (short)*(const unsigned short*)(Asm + (rl0 + e)*BSTR + pl*2);
            int wnx2 = np*2 + ph;
            int kt_g = which*12 + kq*3 + skt;
            *(bf16x8*)(wB3 + (size_t)b*WB_BSTRIDE + (size_t)kt_g*24576
                       + wnx2*6144 + ni2*1024 + lane2*16) = o;
        }
    }
}

// bias2 partials: part2[(b*4+p4)][p] = sum_{n in chunk} biasc[b][n] * w_p[n][p]
__global__ __launch_bounds__(384)
void bvec_k(const float* __restrict__ v, const float* __restrict__ w_p,
            float* __restrict__ part2)
{
    __shared__ float sm[96];
    int p4 = blockIdx.x, b = blockIdx.y, t = threadIdx.x;
    if (t < 96) sm[t] = v[(size_t)b*CC + 96*p4 + t];
    __syncthreads();
    const float* pp = w_p + (size_t)(96*p4)*CC + t;
    float s = 0.f;
    #pragma unroll 8
    for (int e = 0; e < 96; ++e) s += sm[e] * pp[(size_t)e*CC];
    part2[((size_t)b*4 + p4)*CC + t] = s;
}

// Main fused GEMM: out = [A_shift | A] @ Wcomb(b) + bias2(b). 24 BK=32 steps,
// barrier-free, bb[3][3] half-tile depth-2 rotation, M=64.
// launch_bounds (512,6): 3 blocks/CU (LDS 3x52224 = 156672 <= 163840) ->
// 784 blocks / 768 slots = 1.02 rounds (was 1.53 at 2 blocks/CU).
__global__ __launch_bounds__(512, 6)
void gmain(const unsigned short* __restrict__ xt,
           const char* __restrict__ wB3,
           const float* __restrict__ part2,
           const float* __restrict__ b_p,
           float* __restrict__ out)
{
    __shared__ char Asm[68*768];    // 52,224 B: A panel rows m0-2..m0+65

    const int tid = threadIdx.x;
    int bid = blockIdx.x;
    bid = (bid & 7)*(NBLK3/8) + (bid >> 3);       // XCD-chunked swizzle (784=8*98)
    const int b  = bid / MBPB;
    const int m0 = (bid - b*MBPB) * 64;           // batch-local row base
    const size_t gbase = (size_t)b * HWW;

    const int lane = tid & 63;
    const int wid  = tid >> 6;
    const int l16  = lane & 15;
    const int lhi  = lane >> 4;
    const int wm  = (wid >> 2) * 32;              // 2 M-waves, 32 rows each
    const int wnx = wid & 3;                      // 4 N-waves, 96 cols each
    const int wn  = wnx * 96;

    const char* bptr1 = wB3 + (size_t)b*WB_BSTRIDE + wnx*6144 + lane*16;

    int4v bb[3][3];
    #pragma unroll
    for (int e = 0; e < 3; ++e) bb[0][e] = *(const int4v*)(bptr1 + e*1024);
    #pragma unroll
    for (int e = 0; e < 3; ++e) bb[1][e] = *(const int4v*)(bptr1 + 3072 + e*1024);

    // stage A panel (reg-staged, oct-XOR swizzle): 68 rows x 48 octs
    #pragma unroll
    for (int it = 0; it < 7; ++it) {
        int s = it*512 + tid;
        if (s < 68*48) {
            int row = s / 48, oct = s - row*48;
            int g = m0 - 2 + row;
            g = g < 0 ? 0 : (g >= HWW ? HWW-1 : g);
            int4v v = __builtin_nontemporal_load(
                (const int4v*)(xt + (gbase + g)*CC + oct*8));
            *(int4v*)(Asm + row*768 + ((oct ^ (row & 7)) << 4)) = v;
        }
    }

    int rbase[2], hmod[2];
    #pragma unroll
    for (int mi = 0; mi < 2; ++mi) {
        rbase[mi] = wm + mi*16 + l16 + 2;
        hmod[mi]  = (m0 + wm + mi*16 + l16) % HH;
    }

    f32x4 acc[2][6];
    #pragma unroll
    for (int mi = 0; mi < 2; ++mi)
        #pragma unroll
        for (int ni = 0; ni < 6; ++ni) acc[mi][ni] = (f32x4)0.f;

    int4v a[2];
    __syncthreads();   // A panel ready

    // ---- 48 half-steps (24 BK=32 tiles), barrier-free ----
    #pragma unroll
    for (int v = 0; v < 48; ++v) {
        if (v + 2 < 48) {
            const int vn = v + 2, vt = vn >> 1;
            const char* nb = bptr1 + (size_t)vt*24576 + (vn & 1)*3072;
            #pragma unroll
            for (int e = 0; e < 3; ++e)
                bb[vn % 3][e] = *(const int4v*)(nb + e*1024);
        }
        if ((v & 1) == 0) {
            const int kt = v >> 1;
            if (kt < 12) {
                const int octg = kt*4 + lhi;
                const int d = octg < 6 ? 2 : octg < 18 ? 1 : octg < 30 ? 0 : octg < 42 ? -1 : -2;
                #pragma unroll
                for (int mi = 0; mi < 2; ++mi) {
                    int r = rbase[mi] + d;
                    int4v av = *(const int4v*)(Asm + r*768 + ((octg ^ (r & 7)) << 4));
                    int ok = ((unsigned)(hmod[mi] + d) < (unsigned)HH) ? ~0 : 0;
                    a[mi] = av & ok;
                }
            } else {
                const int octg = (kt-12)*4 + lhi;
                #pragma unroll
                for (int mi = 0; mi < 2; ++mi) {
                    int r = rbase[mi];
                    a[mi] = *(const int4v*)(Asm + r*768 + ((octg ^ (r & 7)) << 4));
                }
            }
        }
        __builtin_amdgcn_s_setprio(1);
        #pragma unroll
        for (int mi = 0; mi < 2; ++mi)
            #pragma unroll
            for (int e = 0; e < 3; ++e)
                acc[mi][(v & 1)*3 + e] = __builtin_amdgcn_mfma_f32_16x16x32_bf16(
                    asbf(a[mi]), asbf(bb[v % 3][e]), acc[mi][(v & 1)*3 + e], 0, 0, 0);
        __builtin_amdgcn_s_setprio(0);
    }

    // ---- epilogue: bias2 + un-permute rows (W-major -> H-major), fp32 nontemporal ----
    #pragma unroll
    for (int ni = 0; ni < 6; ++ni) {
        int n = wn + ni*16 + l16;
        float bias = b_p[n]
                   + part2[((size_t)b*4 + 0)*CC + n]
                   + part2[((size_t)b*4 + 1)*CC + n]
                   + part2[((size_t)b*4 + 2)*CC + n]
                   + part2[((size_t)b*4 + 3)*CC + n];
        #pragma unroll
        for (int mi = 0; mi < 2; ++mi) {
            #pragma unroll
            for (int j = 0; j < 4; ++j) {
                int rl = m0 + wm + mi*16 + lhi*4 + j;   // always < HWW
                int hh = rl % HH, ww = rl / HH;
                __builtin_nontemporal_store(acc[mi][ni][j] + bias,
                    out + (gbase + (size_t)(hh*WWD + ww))*CC + n);
            }
        }
    }
}

extern "C" void kernel_launch(void* const* d_in, const int* in_sizes, int n_in,
                              void* d_out, int out_size, void* d_ws, size_t ws_size,
                              hipStream_t stream)
{
    const float* x    = (const float*)d_in[0];
    const float* w_h  = (const float*)d_in[1];
    const float* b_h  = (const float*)d_in[2];
    const float* w_c  = (const float*)d_in[3];
    const float* b_c  = (const float*)d_in[4];
    const float* w_r1 = (const float*)d_in[5];
    const float* b_r1 = (const float*)d_in[6];
    const float* w_r2 = (const float*)d_in[7];
    const float* b_r2 = (const float*)d_in[8];
    const float* w_p  = (const float*)d_in[9];
    const float* b_p  = (const float*)d_in[10];
    float* out = (float*)d_out;

    char* ws = (char*)d_ws;
    unsigned short* xt  = (unsigned short*)(ws);                 // 38,535,168
    char* wB3           = ws + 38535168;                         //  9,437,184
    char* wP3           = ws + 47972352;                         //    294,912
    float* R            = (float*)(ws + 48267264);               //  1,376,256
    float2* lam         = (float2*)(ws + 49643520);              //     49,152
    float* biasc        = (float*)(ws + 49692672);               //     24,576
    float2* part        = (float2*)(ws + 49717248);              //    196,608
    float* part2        = (float*)(ws + 49913856);               //     98,304

    prep_x<<<16*HH, 384, 0, stream>>>(x, xt, R);
    mavec_k<<<dim3(4, 16), 384, 0, stream>>>(R, w_h, w_c, part);
    lam_fin<<<16, 384, 0, stream>>>(part, b_h, b_c, w_r1, b_r1, w_r2, b_r2, lam, biasc);
    prepP_k<<<(12*1536)/256, 256, 0, stream>>>(w_p, wP3);
    wfold_k<<<dim3(4, 2, 32), 512, 0, stream>>>(w_h, w_c, lam, wP3, wB3);
    bvec_k<<<dim3(4, 16), 384, 0, stream>>>(biasc, w_p, part2);
    gmain<<<NBLK3, 512, 0, stream>>>(xt, wB3, part2, b_p, out);
}

// Round 16
// 120.715 us; speedup vs baseline: 4.3766x; 4.3766x over previous
//
#include <hip/hip_runtime.h>
#include <hip/hip_bf16.h>

#define HH 56
#define WWD 56
#define CC 384
#define HWW (HH*WWD)         // 3136
#define MM (16*HWW)          // 50176
#define MBPB 49              // M-blocks (of 64) per batch: 49*64 = 3136 exactly
#define NBLK3 (16*MBPB)      // 784 = 8*98
#define WB_BSTRIDE (24*24576) // 589824 bytes per batch in wB3
#define BSTR 396             // wfold bounce row stride (bytes)

typedef __attribute__((ext_vector_type(8))) short bf16x8;
typedef __attribute__((ext_vector_type(4))) int   int4v;
typedef __attribute__((ext_vector_type(4))) float f32x4;

__device__ __forceinline__ unsigned short f2bf(float f) {
    union { float f; unsigned u; } v; v.f = f;
    unsigned r = v.u + 0x7fffu + ((v.u >> 16) & 1u);
    return (unsigned short)(r >> 16);
}
__device__ __forceinline__ float bf2f(unsigned short h) {
    union { unsigned u; float f; } v; v.u = ((unsigned)h) << 16;
    return v.f;
}
__device__ __forceinline__ bf16x8 asbf(int4v v) {
    union { int4v i; bf16x8 b; } u; u.i = v; return u.b;
}

// K-permutation: [d=+2 (48) | +1 (96) | 0 (96) | -1 (96) | -2 (48)], d[c%8]={2,1,0,-1,-2,-1,0,1}
__device__ __forceinline__ int invp(int k) {
    if (k < 48)  return 8*k;
    if (k < 144) { int j = k-48;  return 8*(j>>1) + ((j&1) ? 7 : 1); }
    if (k < 240) { int j = k-144; return 8*(j>>1) + ((j&1) ? 6 : 2); }
    if (k < 336) { int j = k-240; return 8*(j>>1) + ((j&1) ? 5 : 3); }
    return 8*(k-336) + 4;
}
__device__ __forceinline__ int fwdp(int c) {
    int q = c >> 3, s = c & 7;
    switch (s) {
        case 0: return q;
        case 1: return 48 + 2*q;
        case 7: return 49 + 2*q;
        case 2: return 144 + 2*q;
        case 6: return 145 + 2*q;
        case 3: return 240 + 2*q;
        case 5: return 241 + 2*q;
        default: return 336 + q;
    }
}
__device__ __forceinline__ int dcls(int k) {
    return k < 48 ? 2 : k < 144 ? 1 : k < 240 ? 0 : k < 336 ? -1 : -2;
}

// bid < 16*HH: x (B,H,W,C) fp32 -> xt (B,W,H,Cperm) bf16 + row sums R (R14-proven body)
// bid >= 16*HH: prepP role — w_p into register-fragment order wP3 (12 tiles, K=384)
__global__ __launch_bounds__(384)
void prep_x(const float* __restrict__ x, unsigned short* __restrict__ xt,
            float* __restrict__ R,
            const float* __restrict__ w_p, char* __restrict__ wP3)
{
    __shared__ float buf[4][CC];
    int bid = blockIdx.x;
    int t = threadIdx.x;
    if (bid >= 16*HH) {
        int j = (bid - 16*HH)*384 + t;        // 48 blocks x 384 = 18432 = 12*1536
        int kt = j / 1536, f = j - kt*1536;
        int wnx = f / 384, r = f - wnx*384;
        int ni = r / 64, lane = r - ni*64;
        int n = wnx*96 + ni*16 + (lane & 15);
        int k0 = kt*32 + ((lane >> 4) << 3);
        bf16x8 o;
        #pragma unroll
        for (int e = 0; e < 8; ++e) o[e] = (short)f2bf(w_p[(size_t)(k0 + e)*CC + n]);
        *(bf16x8*)(wP3 + (size_t)kt*24576 + wnx*6144 + ni*1024 + lane*16) = o;
        return;
    }
    int b = bid / HH, h = bid - b*HH;
    int wsub = t / 96, q = t - wsub*96;       // quad q -> channels 4q..4q+3
    int kd0 = fwdp(4*q), kd1 = fwdp(4*q+1), kd2 = fwdp(4*q+2), kd3 = fwdp(4*q+3);
    const float* xp = x + ((size_t)bid*WWD)*CC;
    unsigned short* xo = xt + ((size_t)b*HWW + h)*CC + t;
    float rs = 0.f;
    for (int w0 = 0; w0 < WWD; w0 += 4) {
        float4 v = *(const float4*)(xp + (size_t)(w0 + wsub)*CC + 4*q);
        buf[wsub][kd0] = v.x; buf[wsub][kd1] = v.y;
        buf[wsub][kd2] = v.z; buf[wsub][kd3] = v.w;
        __syncthreads();
        #pragma unroll
        for (int i = 0; i < 4; ++i) {
            float fv = buf[i][t];
            rs += fv;
            xo[(size_t)(w0 + i)*HH*CC] = f2bf(fv);
        }
        __syncthreads();
    }
    R[(size_t)bid*CC + t] = rs;
}

// fused mean (border-corrected, 4x redundant) + partial dual matvec quarter
__global__ __launch_bounds__(384)
void mavec_k(const float* __restrict__ R,
             const float* __restrict__ w_h, const float* __restrict__ w_c,
             float2* __restrict__ part)
{
    __shared__ float mh[CC], mc[CC];
    int p = blockIdx.x, b = blockIdx.y, t = threadIdx.x;
    const float* Rb = R + (size_t)b*HH*CC;
    float S = 0.f;
    #pragma unroll 8
    for (int hh = 0; hh < HH; ++hh) S += Rb[(size_t)hh*CC + t];
    int d = dcls(t);
    float adj = 0.f;
    if (d == 2)       adj = Rb[0*CC + t] + Rb[1*CC + t];
    else if (d == 1)  adj = Rb[0*CC + t];
    else if (d == -1) adj = Rb[55*CC + t];
    else if (d == -2) adj = Rb[54*CC + t] + Rb[55*CC + t];
    const float inv = 1.f / (float)HWW;
    int c = invp(t);
    mh[c] = (S - adj) * inv;
    mc[c] = S * inv;
    __syncthreads();
    const float* ph = w_h + (size_t)(96*p)*CC + t;
    const float* pc = w_c + (size_t)(96*p)*CC + t;
    float sh = 0.f, sc = 0.f;
    #pragma unroll 8
    for (int e = 0; e < 96; ++e) {
        sh += mh[96*p + e] * ph[(size_t)e*CC];
        sc += mc[96*p + e] * pc[(size_t)e*CC];
    }
    part[((size_t)b*4 + p)*CC + t] = make_float2(sh, sc);
}

// combine partials -> a -> GELU MLP -> softmax -> lam + biasc = lh*b_h + lc*b_c
__global__ __launch_bounds__(384)
void lam_fin(const float2* __restrict__ part,
             const float* __restrict__ b_h, const float* __restrict__ b_c,
             const float* __restrict__ w_r1, const float* __restrict__ b_r1,
             const float* __restrict__ w_r2, const float* __restrict__ b_r2,
             float2* __restrict__ lam, float* __restrict__ biasc)
{
    __shared__ float aa[CC], r1p[4][96];
    int b = blockIdx.x, t = threadIdx.x;
    float2 p0 = part[((size_t)b*4 + 0)*CC + t];
    float2 p1 = part[((size_t)b*4 + 1)*CC + t];
    float2 p2 = part[((size_t)b*4 + 2)*CC + t];
    float2 p3 = part[((size_t)b*4 + 3)*CC + t];
    float sh = p0.x + p1.x + p2.x + p3.x;
    float sc = p0.y + p1.y + p2.y + p3.y;
    aa[t] = 2.f*(sh + b_h[t]) + (sc + b_c[t]);
    __syncthreads();
    {
        int j = t % 96, p = t / 96;
        float s = 0.f;
        #pragma unroll 8
        for (int k = p*96; k < p*96 + 96; ++k) s += aa[k] * w_r1[(size_t)k*96 + j];
        r1p[p][j] = s;
    }
    __syncthreads();
    if (t < 96) {
        float s = r1p[0][t] + r1p[1][t] + r1p[2][t] + r1p[3][t] + b_r1[t];
        r1p[0][t] = 0.5f*s*(1.f + erff(s*0.70710678118654752f));
    }
    __syncthreads();
    float s0 = b_r2[3*t], s1 = b_r2[3*t+1], s2 = b_r2[3*t+2];
    #pragma unroll 8
    for (int q = 0; q < 96; ++q) {
        float rv = r1p[0][q];
        const float* wp = w_r2 + (size_t)q*(3*CC) + 3*t;
        s0 += rv*wp[0]; s1 += rv*wp[1]; s2 += rv*wp[2];
    }
    float mx = fmaxf(s0, fmaxf(s1, s2));
    float e0 = expf(s0-mx), e1 = expf(s1-mx), e2 = expf(s2-mx);
    float dn = 1.f/(e0+e1+e2);
    float lh = (e0+e1)*dn, lc = e2*dn;
    lam[(size_t)b*CC + t] = make_float2(lh, lc);
    biasc[(size_t)b*CC + t] = lh*b_h[t] + lc*b_c[t];
}

// Weight fold, N-split (256 blocks): block (kq, which, b, np) computes
// Wcomb[which*384 + kq*96 + row][np*192 + pl] and writes wB3 fragments directly.
__global__ __launch_bounds__(512, 2)
void wfold_k(const float* __restrict__ w_h, const float* __restrict__ w_c,
             const float2* __restrict__ lam, const char* __restrict__ wP3,
             char* __restrict__ wB3)
{
    __shared__ char Asm[96*768];   // 73,728 B; bounce region aliases (96 x BSTR)
    const int tid = threadIdx.x;
    const int kq = blockIdx.x, which = blockIdx.y;
    const int b = blockIdx.z >> 1, np = blockIdx.z & 1;

    const int lane = tid & 63;
    const int wid  = tid >> 6;
    const int l16  = lane & 15;
    const int lhi  = lane >> 4;
    const int mg  = wid >> 2;                     // 2 M-groups, 48 rows each
    const int nw  = wid & 3;
    const int panel = np*2 + (nw >> 1);           // wnx panel (96 cols)
    const int sub   = nw & 1;                     // ni-half within panel

    const char* bptr = wP3 + panel*6144 + sub*3072 + lane*16;
    const float* wsrc = which ? w_c : w_h;

    int4v bb[3][3];
    #pragma unroll
    for (int e = 0; e < 3; ++e) bb[0][e] = *(const int4v*)(bptr + e*1024);
    #pragma unroll
    for (int e = 0; e < 3; ++e) bb[1][e] = *(const int4v*)(bptr + 24576 + e*1024);

    // stage A: 96 rows x 48 octs (lam-scaled bf16, oct-XOR swizzle, stride 768)
    #pragma unroll
    for (int it = 0; it < 9; ++it) {
        int s = it*512 + tid;
        if (s < 96*48) {
            int rr = s / 48, oct = s - rr*48;
            int c = invp(kq*96 + rr);
            const float* src = wsrc + (size_t)c*CC + oct*8;
            const float2* lp = lam + (size_t)b*CC + oct*8;
            bf16x8 o;
            #pragma unroll
            for (int e = 0; e < 8; ++e) {
                float2 L = lp[e];
                float s_ = which ? L.y : L.x;
                o[e] = (short)f2bf(src[e] * s_);
            }
            *(bf16x8*)(Asm + rr*768 + ((oct ^ (rr & 7)) << 4)) = o;
        }
    }

    f32x4 acc[3][3];
    #pragma unroll
    for (int mi = 0; mi < 3; ++mi)
        #pragma unroll
        for (int e = 0; e < 3; ++e) acc[mi][e] = (f32x4)0.f;

    int4v a[3];
    __syncthreads();

    #pragma unroll
    for (int kt = 0; kt < 12; ++kt) {
        if (kt + 2 < 12) {
            const char* nb = bptr + (size_t)(kt+2)*24576;
            #pragma unroll
            for (int e = 0; e < 3; ++e)
                bb[(kt+2) % 3][e] = *(const int4v*)(nb + e*1024);
        }
        const int octg = kt*4 + lhi;
        #pragma unroll
        for (int mi = 0; mi < 3; ++mi) {
            int r = mg*48 + mi*16 + l16;
            a[mi] = *(const int4v*)(Asm + r*768 + ((octg ^ (r & 7)) << 4));
        }
        #pragma unroll
        for (int mi = 0; mi < 3; ++mi)
            #pragma unroll
            for (int e = 0; e < 3; ++e)
                acc[mi][e] = __builtin_amdgcn_mfma_f32_16x16x32_bf16(
                    asbf(a[mi]), asbf(bb[kt % 3][e]), acc[mi][e], 0, 0, 0);
    }

    __syncthreads();   // done reading A region

    // bounce: acc -> LDS[row][pl] bf16, stride BSTR (pl local col 0..191)
    #pragma unroll
    for (int e = 0; e < 3; ++e) {
        int pl = (nw >> 1)*96 + sub*48 + e*16 + l16;
        #pragma unroll
        for (int mi = 0; mi < 3; ++mi) {
            int row0 = mg*48 + mi*16 + lhi*4;
            #pragma unroll
            for (int j = 0; j < 4; ++j)
                *(unsigned short*)(Asm + (row0 + j)*BSTR + pl*2) = f2bf(acc[mi][e][j]);
        }
    }
    __syncthreads();

    // gather fragments: 3 skt x 2 ph x 6 ni2 x 64 lanes = 2304 frags (5 iters)
    #pragma unroll
    for (int fi = 0; fi < 5; ++fi) {
        int flat = fi*512 + tid;
        if (flat < 2304) {
            int lane2 = flat & 63;
            int t2 = flat >> 6;
            int ni2 = t2 % 6;
            int t3 = t2 / 6;
            int ph = t3 & 1;
            int skt = t3 >> 1;
            int pl = ph*96 + ni2*16 + (lane2 & 15);
            int rl0 = skt*32 + ((lane2 >> 4) << 3);
            bf16x8 o;
            #pragma unroll
            for (int e = 0; e < 8; ++e)
                o[e] = (short)*(const unsigned short*)(Asm + (rl0 + e)*BSTR + pl*2);
            int wnx2 = np*2 + ph;
            int kt_g = which*12 + kq*3 + skt;
            *(bf16x8*)(wB3 + (size_t)b*WB_BSTRIDE + (size_t)kt_g*24576
                       + wnx2*6144 + ni2*1024 + lane2*16) = o;
        }
    }
}

// bias2 partials: part2[(b*4+p4)][p] = sum_{n in chunk} biasc[b][n] * w_p[n][p]
__global__ __launch_bounds__(384)
void bvec_k(const float* __restrict__ v, const float* __restrict__ w_p,
            float* __restrict__ part2)
{
    __shared__ float sm[96];
    int p4 = blockIdx.x, b = blockIdx.y, t = threadIdx.x;
    if (t < 96) sm[t] = v[(size_t)b*CC + 96*p4 + t];
    __syncthreads();
    const float* pp = w_p + (size_t)(96*p4)*CC + t;
    float s = 0.f;
    #pragma unroll 8
    for (int e = 0; e < 96; ++e) s += sm[e] * pp[(size_t)e*CC];
    part2[((size_t)b*4 + p4)*CC + t] = s;
}

// Main fused GEMM (R12/R14-proven): out = [A_shift | A] @ Wcomb(b) + bias2(b).
// 24 BK=32 steps, barrier-free, bb[3][3] half-tile depth-2 rotation, M=64, 2 blocks/CU.
__global__ __launch_bounds__(512, 4)
void gmain(const unsigned short* __restrict__ xt,
           const char* __restrict__ wB3,
           const float* __restrict__ part2,
           const float* __restrict__ b_p,
           float* __restrict__ out)
{
    __shared__ char Asm[68*768];    // 52,224 B: A panel rows m0-2..m0+65

    const int tid = threadIdx.x;
    int bid = blockIdx.x;
    bid = (bid & 7)*(NBLK3/8) + (bid >> 3);       // XCD-chunked swizzle (784=8*98)
    const int b  = bid / MBPB;
    const int m0 = (bid - b*MBPB) * 64;           // batch-local row base
    const size_t gbase = (size_t)b * HWW;

    const int lane = tid & 63;
    const int wid  = tid >> 6;
    const int l16  = lane & 15;
    const int lhi  = lane >> 4;
    const int wm  = (wid >> 2) * 32;              // 2 M-waves, 32 rows each
    const int wnx = wid & 3;                      // 4 N-waves, 96 cols each
    const int wn  = wnx * 96;

    const char* bptr1 = wB3 + (size_t)b*WB_BSTRIDE + wnx*6144 + lane*16;

    int4v bb[3][3];
    #pragma unroll
    for (int e = 0; e < 3; ++e) bb[0][e] = *(const int4v*)(bptr1 + e*1024);
    #pragma unroll
    for (int e = 0; e < 3; ++e) bb[1][e] = *(const int4v*)(bptr1 + 3072 + e*1024);

    // stage A panel (reg-staged, oct-XOR swizzle): 68 rows x 48 octs
    #pragma unroll
    for (int it = 0; it < 7; ++it) {
        int s = it*512 + tid;
        if (s < 68*48) {
            int row = s / 48, oct = s - row*48;
            int g = m0 - 2 + row;
            g = g < 0 ? 0 : (g >= HWW ? HWW-1 : g);
            int4v v = __builtin_nontemporal_load(
                (const int4v*)(xt + (gbase + g)*CC + oct*8));
            *(int4v*)(Asm + row*768 + ((oct ^ (row & 7)) << 4)) = v;
        }
    }

    int rbase[2], hmod[2];
    #pragma unroll
    for (int mi = 0; mi < 2; ++mi) {
        rbase[mi] = wm + mi*16 + l16 + 2;
        hmod[mi]  = (m0 + wm + mi*16 + l16) % HH;
    }

    f32x4 acc[2][6];
    #pragma unroll
    for (int mi = 0; mi < 2; ++mi)
        #pragma unroll
        for (int ni = 0; ni < 6; ++ni) acc[mi][ni] = (f32x4)0.f;

    int4v a[2];
    __syncthreads();   // A panel ready

    // ---- 48 half-steps (24 BK=32 tiles), barrier-free ----
    #pragma unroll
    for (int v = 0; v < 48; ++v) {
        if (v + 2 < 48) {
            const int vn = v + 2, vt = vn >> 1;
            const char* nb = bptr1 + (size_t)vt*24576 + (vn & 1)*3072;
            #pragma unroll
            for (int e = 0; e < 3; ++e)
                bb[vn % 3][e] = *(const int4v*)(nb + e*1024);
        }
        if ((v & 1) == 0) {
            const int kt = v >> 1;
            if (kt < 12) {
                const int octg = kt*4 + lhi;
                const int d = octg < 6 ? 2 : octg < 18 ? 1 : octg < 30 ? 0 : octg < 42 ? -1 : -2;
                #pragma unroll
                for (int mi = 0; mi < 2; ++mi) {
                    int r = rbase[mi] + d;
                    int4v av = *(const int4v*)(Asm + r*768 + ((octg ^ (r & 7)) << 4));
                    int ok = ((unsigned)(hmod[mi] + d) < (unsigned)HH) ? ~0 : 0;
                    a[mi] = av & ok;
                }
            } else {
                const int octg = (kt-12)*4 + lhi;
                #pragma unroll
                for (int mi = 0; mi < 2; ++mi) {
                    int r = rbase[mi];
                    a[mi] = *(const int4v*)(Asm + r*768 + ((octg ^ (r & 7)) << 4));
                }
            }
        }
        __builtin_amdgcn_s_setprio(1);
        #pragma unroll
        for (int mi = 0; mi < 2; ++mi)
            #pragma unroll
            for (int e = 0; e < 3; ++e)
                acc[mi][(v & 1)*3 + e] = __builtin_amdgcn_mfma_f32_16x16x32_bf16(
                    asbf(a[mi]), asbf(bb[v % 3][e]), acc[mi][(v & 1)*3 + e], 0, 0, 0);
        __builtin_amdgcn_s_setprio(0);
    }

    // ---- epilogue: bias2 + un-permute rows (W-major -> H-major), fp32 nontemporal ----
    #pragma unroll
    for (int ni = 0; ni < 6; ++ni) {
        int n = wn + ni*16 + l16;
        float bias = b_p[n]
                   + part2[((size_t)b*4 + 0)*CC + n]
                   + part2[((size_t)b*4 + 1)*CC + n]
                   + part2[((size_t)b*4 + 2)*CC + n]
                   + part2[((size_t)b*4 + 3)*CC + n];
        #pragma unroll
        for (int mi = 0; mi < 2; ++mi) {
            #pragma unroll
            for (int j = 0; j < 4; ++j) {
                int rl = m0 + wm + mi*16 + lhi*4 + j;   // always < HWW
                int hh = rl % HH, ww = rl / HH;
                __builtin_nontemporal_store(acc[mi][ni][j] + bias,
                    out + (gbase + (size_t)(hh*WWD + ww))*CC + n);
            }
        }
    }
}

extern "C" void kernel_launch(void* const* d_in, const int* in_sizes, int n_in,
                              void* d_out, int out_size, void* d_ws, size_t ws_size,
                              hipStream_t stream)
{
    const float* x    = (const float*)d_in[0];
    const float* w_h  = (const float*)d_in[1];
    const float* b_h  = (const float*)d_in[2];
    const float* w_c  = (const float*)d_in[3];
    const float* b_c  = (const float*)d_in[4];
    const float* w_r1 = (const float*)d_in[5];
    const float* b_r1 = (const float*)d_in[6];
    const float* w_r2 = (const float*)d_in[7];
    const float* b_r2 = (const float*)d_in[8];
    const float* w_p  = (const float*)d_in[9];
    const float* b_p  = (const float*)d_in[10];
    float* out = (float*)d_out;

    char* ws = (char*)d_ws;
    unsigned short* xt  = (unsigned short*)(ws);                 // 38,535,168
    char* wB3           = ws + 38535168;                         //  9,437,184
    char* wP3           = ws + 47972352;                         //    294,912
    float* R            = (float*)(ws + 48267264);               //  1,376,256
    float2* lam         = (float2*)(ws + 49643520);              //     49,152
    float* biasc        = (float*)(ws + 49692672);               //     24,576
    float2* part        = (float2*)(ws + 49717248);              //    196,608
    float* part2        = (float*)(ws + 49913856);               //     98,304

    prep_x<<<16*HH + 48, 384, 0, stream>>>(x, xt, R, w_p, wP3);
    mavec_k<<<dim3(4, 16), 384, 0, stream>>>(R, w_h, w_c, part);
    lam_fin<<<16, 384, 0, stream>>>(part, b_h, b_c, w_r1, b_r1, w_r2, b_r2, lam, biasc);
    wfold_k<<<dim3(4, 2, 32), 512, 0, stream>>>(w_h, w_c, lam, wP3, wB3);
    bvec_k<<<dim3(4, 16), 384, 0, stream>>>(biasc, w_p, part2);
    gmain<<<NBLK3, 512, 0, stream>>>(xt, wB3, part2, b_p, out);
}